// Round 1
// baseline (314.277 us; speedup 1.0000x reference)
//
#include <hip/hip_runtime.h>
#include <math.h>
#include <stdint.h>

// ---------------------------------------------------------------------------
// Mlp_8744553415182 on MI355X (gfx950). FP32 I/O; bf16 MFMA compute.
//   1. prep_kernel:  x->xb(+xpad,s_x), W1->w1b(+w1pad,s_w), W2->w2b, s_b, counts=0
//   2. gemm1_topk:   z=0 blocks: h = gelu(x.W1^T+b1) (MFMA K=1024, slab epilogue)
//                    z=1 blocks: counts[n] += #(x_topk.w1_topk+b1 > 0) (K=128)
//   3. fixup_kernel: channels with counts<=2048 -> exact quantized path
//   4. gemm2_bias:   out = h.W2^T + b2, FP32 out (MFMA K=4096, 128x64 tile)
// R6->R7: gemm cores restructured from stage->drain->compute (implicit
// s_waitcnt vmcnt(0) at every __syncthreads: the m97-structure ceiling) to a
// ring-of-3 LDS slot pipeline with 2-tile prefetch lookahead and COUNTED
// vmcnt (T4): raw s_barrier + asm "s_waitcnt vmcnt(8/6)" in the main loop
// (never 0), vmcnt(4/3)->vmcnt(0) tail, setprio(1) around MFMA (T5).
// Slot ledger: iter t stages tile t+2 into the slot tile t-1 vacated (all
// waves passed t-1's closing barrier before the stage issues -> race-free).
// XOR swizzle (R3: 0 conflicts) + slab epilogues (R5: WRITE ideal) kept.
// ---------------------------------------------------------------------------

typedef __bf16 v8bf __attribute__((ext_vector_type(8)));
typedef float v4f __attribute__((ext_vector_type(4)));
typedef unsigned short v8us __attribute__((ext_vector_type(8)));

#define AS_G __attribute__((address_space(1)))
#define AS_L __attribute__((address_space(3)))

#define GLOAD(gp, lp) __builtin_amdgcn_global_load_lds((const AS_G void*)(gp), (AS_L void*)(lp), 16, 0, 0)

__device__ __forceinline__ unsigned short f2bf(float f) {
    union { float f; unsigned int i; } v; v.f = f;
    unsigned int r = v.i + 0x7fffu + ((v.i >> 16) & 1u);   // RNE
    return (unsigned short)(r >> 16);
}
__device__ __forceinline__ float gelu_fast(float v) {
    float u = v * (0.79788456080286536f + 0.035677408136300125f * v * v);
    u = fminf(fmaxf(u, -15.f), 15.f);
    float e = __expf(2.0f * u);
    return v * e * __builtin_amdgcn_rcpf(e + 1.0f);   // v*e/(e+1) = 0.5v(1+tanh u)
}
__device__ __forceinline__ float gelu_exact(float v) {
    return 0.5f * v * (1.0f + erff(v * 0.70710678118654752440f));
}

// --------------------------- MFMA GEMM core (BK=32, 128x128 tile) -----------
// Ring of 3 slots x 16KB (A 8KB | B 8KB). 4 waves 2x2, acc[4][4].
// XOR swizzle (R3-verified conflict-free): 16B-chunk l of each 1KB block holds
// (row=l>>2, colblk=(l&3)^((l>>3)&3)); reader roff = R*32 + (Q^((R>>1)&3))*8.
// Pipeline: stage t+2 -> vmcnt(8) [tiles t+1,t+2 stay in flight] -> barrier ->
// ds_read+MFMA tile t -> barrier. Tail: vmcnt(4) then vmcnt(0).
__device__ __forceinline__ void gemm_core(const unsigned short* __restrict__ A,
                                          const unsigned short* __restrict__ B,
                                          int K, int bm0, int bn0,
                                          unsigned short* lds,
                                          v4f acc[4][4])
{
    const int tid  = threadIdx.x;
    const int wave = tid >> 6;
    const int lane = tid & 63;
    const int rowInChunk = lane >> 2;
    const int col8 = ((lane & 3) ^ ((lane >> 3) & 3)) * 8;
    const int ldsLane = lane * 8;
    const int c0 = wave * 2, c1 = wave * 2 + 1;
    const int wm = wave & 1, wn = wave >> 1;

    const size_t aR0 = (size_t)(bm0 + c0 * 16 + rowInChunk) * K + col8;
    const size_t aR1 = (size_t)(bm0 + c1 * 16 + rowInChunk) * K + col8;
    const size_t bR0 = (size_t)(bn0 + c0 * 16 + rowInChunk) * K + col8;
    const size_t bR1 = (size_t)(bn0 + c1 * 16 + rowInChunk) * K + col8;

    const int R = lane & 15, Q = lane >> 4;
    const int roff = R * 32 + ((Q ^ ((R >> 1) & 3)) * 8);
    const int NT = K >> 5;

#define G1_STAGE(t, slab)                                                     \
    {   const int k0_ = (t) << 5; unsigned short* s_ = (slab);                \
        GLOAD(A + aR0 + k0_, s_ + c0 * 512 + ldsLane);                        \
        GLOAD(A + aR1 + k0_, s_ + c1 * 512 + ldsLane);                        \
        GLOAD(B + bR0 + k0_, s_ + 4096 + c0 * 512 + ldsLane);                 \
        GLOAD(B + bR1 + k0_, s_ + 4096 + c1 * 512 + ldsLane);   }

#define G1_COMPUTE(slab)                                                      \
    {   const unsigned short* s_ = (slab);                                    \
        v8bf af[4], bfr[4];                                                   \
        _Pragma("unroll")                                                     \
        for (int i = 0; i < 4; ++i)                                           \
            af[i] = *(const v8bf*)&s_[(wm * 4 + i) * 512 + roff];             \
        _Pragma("unroll")                                                     \
        for (int j = 0; j < 4; ++j)                                           \
            bfr[j] = *(const v8bf*)&s_[4096 + (wn * 4 + j) * 512 + roff];     \
        __builtin_amdgcn_s_setprio(1);                                        \
        _Pragma("unroll")                                                     \
        for (int i = 0; i < 4; ++i)                                           \
        _Pragma("unroll")                                                     \
        for (int j = 0; j < 4; ++j)                                           \
            acc[i][j] = __builtin_amdgcn_mfma_f32_16x16x32_bf16(af[i], bfr[j], acc[i][j], 0, 0, 0); \
        __builtin_amdgcn_s_setprio(0);   }

    // prologue: tiles 0,1 -> slots 0,1
    G1_STAGE(0, lds);
    G1_STAGE(1, lds + 8192);
    unsigned short* pc = lds;               // compute slot: t   % 3
    unsigned short* ps = lds + 16384;       // stage slot:  t+2 % 3

    for (int t = 0; t < NT - 2; ++t) {
        G1_STAGE(t + 2, ps);
        asm volatile("s_waitcnt vmcnt(8)" ::: "memory");   // tile t arrived; t+1,t+2 in flight
        __builtin_amdgcn_s_barrier();
        __builtin_amdgcn_sched_barrier(0);
        G1_COMPUTE(pc);
        __builtin_amdgcn_s_barrier();
        ps = pc;                                           // slot t vacated -> stage target for t+3
        pc = (pc == lds + 16384) ? lds : pc + 8192;
    }
    // tail tile NT-2 (only tile NT-1's 4 loads younger)
    asm volatile("s_waitcnt vmcnt(4)" ::: "memory");
    __builtin_amdgcn_s_barrier();
    __builtin_amdgcn_sched_barrier(0);
    G1_COMPUTE(pc);
    __builtin_amdgcn_s_barrier();
    pc = (pc == lds + 16384) ? lds : pc + 8192;
    // tail tile NT-1
    asm volatile("s_waitcnt vmcnt(0)" ::: "memory");
    __builtin_amdgcn_s_barrier();
    __builtin_amdgcn_sched_barrier(0);
    G1_COMPUTE(pc);
    __builtin_amdgcn_s_barrier();
#undef G1_STAGE
#undef G1_COMPUTE
}

// 128x64 tile variant: ring of 3 slots x 12KB (A 8KB | B 4KB), acc[4][2].
// 3 loads/stage -> steady vmcnt(6), tail vmcnt(3) then vmcnt(0).
__device__ __forceinline__ void gemm_core64N(const unsigned short* __restrict__ A,
                                             const unsigned short* __restrict__ B,
                                             int K, int bm0, int bn0,
                                             unsigned short* lds,
                                             v4f acc[4][2])
{
    const int tid  = threadIdx.x;
    const int wave = tid >> 6;
    const int lane = tid & 63;
    const int rowInChunk = lane >> 2;
    const int col8 = ((lane & 3) ^ ((lane >> 3) & 3)) * 8;
    const int ldsLane = lane * 8;
    const int c0 = wave * 2, c1 = wave * 2 + 1;
    const int wm = wave & 1, wn = wave >> 1;

    const size_t aR0 = (size_t)(bm0 + c0 * 16 + rowInChunk) * K + col8;
    const size_t aR1 = (size_t)(bm0 + c1 * 16 + rowInChunk) * K + col8;
    const size_t bR  = (size_t)(bn0 + wave * 16 + rowInChunk) * K + col8;

    const int R = lane & 15, Q = lane >> 4;
    const int roff = R * 32 + ((Q ^ ((R >> 1) & 3)) * 8);
    const int NT = K >> 5;

#define G2_STAGE(t, slab)                                                     \
    {   const int k0_ = (t) << 5; unsigned short* s_ = (slab);                \
        GLOAD(A + aR0 + k0_, s_ + c0 * 512 + ldsLane);                        \
        GLOAD(A + aR1 + k0_, s_ + c1 * 512 + ldsLane);                        \
        GLOAD(B + bR  + k0_, s_ + 4096 + wave * 512 + ldsLane);   }

#define G2_COMPUTE(slab)                                                      \
    {   const unsigned short* s_ = (slab);                                    \
        v8bf af[4], bfr[2];                                                   \
        _Pragma("unroll")                                                     \
        for (int i = 0; i < 4; ++i)                                           \
            af[i] = *(const v8bf*)&s_[(wm * 4 + i) * 512 + roff];             \
        _Pragma("unroll")                                                     \
        for (int j = 0; j < 2; ++j)                                           \
            bfr[j] = *(const v8bf*)&s_[4096 + (wn * 2 + j) * 512 + roff];     \
        __builtin_amdgcn_s_setprio(1);                                        \
        _Pragma("unroll")                                                     \
        for (int i = 0; i < 4; ++i)                                           \
        _Pragma("unroll")                                                     \
        for (int j = 0; j < 2; ++j)                                           \
            acc[i][j] = __builtin_amdgcn_mfma_f32_16x16x32_bf16(af[i], bfr[j], acc[i][j], 0, 0, 0); \
        __builtin_amdgcn_s_setprio(0);   }

    G2_STAGE(0, lds);
    G2_STAGE(1, lds + 6144);
    unsigned short* pc = lds;
    unsigned short* ps = lds + 12288;

    for (int t = 0; t < NT - 2; ++t) {
        G2_STAGE(t + 2, ps);
        asm volatile("s_waitcnt vmcnt(6)" ::: "memory");
        __builtin_amdgcn_s_barrier();
        __builtin_amdgcn_sched_barrier(0);
        G2_COMPUTE(pc);
        __builtin_amdgcn_s_barrier();
        ps = pc;
        pc = (pc == lds + 12288) ? lds : pc + 6144;
    }
    asm volatile("s_waitcnt vmcnt(3)" ::: "memory");
    __builtin_amdgcn_s_barrier();
    __builtin_amdgcn_sched_barrier(0);
    G2_COMPUTE(pc);
    __builtin_amdgcn_s_barrier();
    pc = (pc == lds + 12288) ? lds : pc + 6144;
    asm volatile("s_waitcnt vmcnt(0)" ::: "memory");
    __builtin_amdgcn_s_barrier();
    __builtin_amdgcn_sched_barrier(0);
    G2_COMPUTE(pc);
    __builtin_amdgcn_s_barrier();
#undef G2_STAGE
#undef G2_COMPUTE
}

// --------------------------- prep (fused) -----------------------------------
__global__ void prep_kernel(const float* __restrict__ x, const float* __restrict__ W1,
                            const float* __restrict__ W2, const float* __restrict__ b1,
                            unsigned short* __restrict__ xb, unsigned short* __restrict__ w1b,
                            unsigned short* __restrict__ w2b,
                            unsigned short* __restrict__ xpad, unsigned short* __restrict__ w1pad,
                            float* __restrict__ s_x, float* __restrict__ s_w,
                            float* __restrict__ s_b, int* __restrict__ counts)
{
    const int b = blockIdx.x, t = threadIdx.x;
    __shared__ float red[4];

    if (b < 16384) {
        const float* src; unsigned short* dst; unsigned short* pad = nullptr; float* sc = nullptr;
        if (b < 8192)       { src = x  + (size_t)b * 1024;            dst = xb  + (size_t)b * 1024;
                              pad = xpad  + (size_t)b * 128;          sc = s_x + b; }
        else if (b < 12288) { int r = b - 8192;  src = W1 + (size_t)r * 1024; dst = w1b + (size_t)r * 1024;
                              pad = w1pad + (size_t)r * 128;          sc = s_w + r; }
        else                { int r = b - 12288; src = W2 + (size_t)r * 1024; dst = w2b + (size_t)r * 1024; }

        float4 v = ((const float4*)src)[t];
        ushort4 u;
        u.x = f2bf(v.x); u.y = f2bf(v.y); u.z = f2bf(v.z); u.w = f2bf(v.w);
        ((ushort4*)dst)[t] = u;
        if (pad && t < 32) {
            int c = t * 4;
            ushort4 p;
            p.x = (c + 0 < 103) ? u.x : (unsigned short)0;
            p.y = (c + 1 < 103) ? u.y : (unsigned short)0;
            p.z = (c + 2 < 103) ? u.z : (unsigned short)0;
            p.w = (c + 3 < 103) ? u.w : (unsigned short)0;
            ((ushort4*)pad)[t] = p;
        }
        if (sc) {
            float m = fmaxf(fmaxf(fabsf(v.x), fabsf(v.y)), fmaxf(fabsf(v.z), fabsf(v.w)));
#pragma unroll
            for (int off = 32; off; off >>= 1) m = fmaxf(m, __shfl_xor(m, off, 64));
            if ((t & 63) == 0) red[t >> 6] = m;
            __syncthreads();
            if (t == 0) {
                m = fmaxf(fmaxf(red[0], red[1]), fmaxf(red[2], red[3]));
                *sc = fmaxf(m, 1e-5f) * (1.0f / 127.0f);
            }
        }
    } else {
        float m = 0.f;
        for (int k = t; k < 4096; k += 256) { m = fmaxf(m, fabsf(b1[k])); counts[k] = 0; }
#pragma unroll
        for (int off = 32; off; off >>= 1) m = fmaxf(m, __shfl_xor(m, off, 64));
        if ((t & 63) == 0) red[t >> 6] = m;
        __syncthreads();
        if (t == 0) {
            m = fmaxf(fmaxf(red[0], red[1]), fmaxf(red[2], red[3]));
            *s_b = fmaxf(m, 1e-5f) * (1.0f / 127.0f);
        }
    }
}

// --------------------------- gemm1 + topk (fused dispatch) -------------------
// z=0 (64x32 blocks): h = gelu(x.W1^T + b1), slab epilogue.
// z=1 (64x32 blocks): topk counts (K=128 on padded operands) — finish in 4
// K-iters and free CU slots back to gemm1 blocks.
__global__ __launch_bounds__(256, 3)
void gemm1_topk(const unsigned short* __restrict__ xb,
                const unsigned short* __restrict__ w1b,
                const unsigned short* __restrict__ xpad,
                const unsigned short* __restrict__ w1pad,
                const float* __restrict__ b1,
                unsigned short* __restrict__ hbuf,
                int* __restrict__ counts)
{
    __shared__ unsigned short lds[24576];   // 48 KB: 3 ring slots x 16 KB
    v4f acc[4][4];
    v4f z = {0.f, 0.f, 0.f, 0.f};
#pragma unroll
    for (int i = 0; i < 4; ++i)
#pragma unroll
        for (int j = 0; j < 4; ++j) acc[i][j] = z;

    const int bm0 = blockIdx.x * 128, bn0 = blockIdx.y * 128;
    const int tid = threadIdx.x;
    const int lane = tid & 63, wave = tid >> 6;
    const int wm = wave & 1, wn = wave >> 1, q = lane >> 4;

    if (blockIdx.z == 0) {
        gemm_core(xb, w1b, 1024, bm0, bn0, lds, acc);

        float bvj[4];
#pragma unroll
        for (int j = 0; j < 4; ++j) bvj[j] = b1[bn0 + wn * 64 + j * 16 + (lane & 15)];

#pragma unroll
        for (int p = 0; p < 2; ++p) {
            __syncthreads();
            if (wm == p) {
#pragma unroll
                for (int j = 0; j < 4; ++j) {
                    int nl = wn * 64 + j * 16 + (lane & 15);
#pragma unroll
                    for (int i = 0; i < 4; ++i)
#pragma unroll
                        for (int r = 0; r < 4; ++r)
                            lds[(i * 16 + q * 4 + r) * 128 + nl] =
                                f2bf(gelu_fast(acc[i][j][r] + bvj[j]));
                }
            }
            __syncthreads();
#pragma unroll
            for (int s = 0; s < 4; ++s) {
                int c = s * 256 + tid;
                int row = c >> 4, ch = c & 15;
                *(v8us*)&hbuf[(size_t)(bm0 + p * 64 + row) * 4096 + bn0 + ch * 8] =
                    *(const v8us*)&lds[row * 128 + ch * 8];
            }
        }
    } else {
        gemm_core(xpad, w1pad, 128, bm0, bn0, lds, acc);

#pragma unroll
        for (int j = 0; j < 4; ++j) {
            int n = bn0 + wn * 64 + j * 16 + (lane & 15);
            float bv = b1[n];
            int cnt = 0;
#pragma unroll
            for (int i = 0; i < 4; ++i)
#pragma unroll
                for (int r = 0; r < 4; ++r)
                    cnt += (acc[i][j][r] + bv > 0.0f) ? 1 : 0;
            cnt += __shfl_xor(cnt, 16, 64);
            cnt += __shfl_xor(cnt, 32, 64);
            if (lane < 16 && cnt) atomicAdd(&counts[n], cnt);
        }
    }
}

// --------------------------- fixup (exact quant path) ------------------------
__global__ void fixup_kernel(const float* __restrict__ x,
                             const float* __restrict__ W1,
                             const float* __restrict__ b1,
                             const int* __restrict__ counts,
                             const float* __restrict__ s_x,
                             const float* __restrict__ s_w,
                             const float* __restrict__ s_b,
                             unsigned short* __restrict__ hbuf)
{
    const int n = blockIdx.x;
    if (counts[n] > 2048) return;   // fp channel: keep gemm1 result
    __shared__ float qw[1024];
    const float swn = s_w[n];
    for (int k = threadIdx.x; k < 1024; k += 256) {
        float q = nearbyintf(W1[(size_t)n * 1024 + k] / swn);
        qw[k] = fminf(fmaxf(q, -128.f), 127.f) * swn;
    }
    __syncthreads();
    const float sb = *s_b;
    const float bq = fminf(fmaxf(nearbyintf(b1[n] / sb), -128.f), 127.f) * sb;
    for (int m = threadIdx.x; m < 8192; m += 256) {
        const float sxm = s_x[m];
        float a = 0.f;
        for (int k = 0; k < 1024; ++k) {
            float q = nearbyintf(x[(size_t)m * 1024 + k] / sxm);
            a += fminf(fmaxf(q, -128.f), 127.f) * sxm * qw[k];
        }
        hbuf[(size_t)m * 4096 + n] = f2bf(gelu_exact(a + bq));
    }
}

// --------------------------- gemm2 + bias (128x64 tile) ----------------------
// 1024 blocks -> 4 blocks/CU. Ring-3 pipelined core (36 KB LDS).
// Epilogue: 4 passes of a 32x64 fp32 LDS slab (8 KB), coalesced float4 out.
__global__ __launch_bounds__(256, 4)
void gemm2_bias(const unsigned short* __restrict__ hbuf,
                const unsigned short* __restrict__ w2b,
                const float* __restrict__ b2,
                float* __restrict__ out)
{
    __shared__ unsigned short lds[18432];   // 36 KB: 3 ring slots x 12 KB
    v4f acc[4][2];
    v4f z = {0.f, 0.f, 0.f, 0.f};
#pragma unroll
    for (int i = 0; i < 4; ++i)
#pragma unroll
        for (int j = 0; j < 2; ++j) acc[i][j] = z;

    const int bm0 = blockIdx.x * 128, bn0 = blockIdx.y * 64;
    gemm_core64N(hbuf, w2b, 4096, bm0, bn0, lds, acc);

    const int tid = threadIdx.x;
    const int lane = tid & 63, wave = tid >> 6;
    const int wm = wave & 1, wn = wave >> 1, q = lane >> 4;
    float* ldsf = (float*)lds;             // 32x64 slab = 8 KB

    float bvj[2];
#pragma unroll
    for (int j = 0; j < 2; ++j) bvj[j] = b2[bn0 + wn * 32 + j * 16 + (lane & 15)];

#pragma unroll
    for (int p = 0; p < 4; ++p) {
        __syncthreads();
        if (wm == (p >> 1)) {
            const int ibase = (p & 1) * 2;
#pragma unroll
            for (int ii = 0; ii < 2; ++ii) {
#pragma unroll
                for (int j = 0; j < 2; ++j) {
                    int nl = wn * 32 + j * 16 + (lane & 15);
#pragma unroll
                    for (int r = 0; r < 4; ++r)
                        ldsf[(ii * 16 + q * 4 + r) * 64 + nl] =
                            acc[ibase + ii][j][r] + bvj[j];
                }
            }
        }
        __syncthreads();
#pragma unroll
        for (int s = 0; s < 2; ++s) {
            int c = s * 256 + tid;           // 0..511
            int row = c >> 4, ch = c & 15;   // 32 rows x 16 chunks of 16B
            *(float4*)&out[(size_t)(bm0 + p * 32 + row) * 1024 + bn0 + ch * 4] =
                *(const float4*)&ldsf[row * 64 + ch * 4];
        }
    }
}

// --------------------------- launch ----------------------------------------
extern "C" void kernel_launch(void* const* d_in, const int* in_sizes, int n_in,
                              void* d_out, int out_size, void* d_ws, size_t ws_size,
                              hipStream_t stream)
{
    const float* x  = (const float*)d_in[0];   // [4,2048,1024] fp32
    const float* W1 = (const float*)d_in[1];   // [4096,1024]
    const float* b1 = (const float*)d_in[2];   // [4096]
    const float* W2 = (const float*)d_in[3];   // [1024,4096]
    const float* b2 = (const float*)d_in[4];   // [1024]
    float* out = (float*)d_out;                // [4,2048,1024] fp32 (32 MB)

    // bf16 copies of x and W1 parked in d_out (dead until gemm2 writes it):
    unsigned short* xb  = (unsigned short*)d_out;                       // 16 MB
    unsigned short* w1b = (unsigned short*)d_out + (size_t)8192 * 1024; // 8 MB

    char* ws = (char*)d_ws;
    int*   counts = (int*)(ws + 0);                       // 16 KB
    float* s_x    = (float*)(ws + (64 << 10));            // 32 KB
    float* s_w    = (float*)(ws + (96 << 10));            // 16 KB
    float* s_b    = (float*)(ws + (112 << 10));           // 4 B
    unsigned short* xpad  = (unsigned short*)(ws + (1 << 20));   // 2 MB
    unsigned short* w1pad = (unsigned short*)(ws + (3 << 20));   // 1 MB
    unsigned short* w2b   = (unsigned short*)(ws + (4 << 20));   // 8 MB
    unsigned short* hbuf  = (unsigned short*)(ws + (12 << 20));  // 64 MB -> 76 MB total

    prep_kernel<<<16385, 256, 0, stream>>>(x, W1, W2, b1, xb, w1b, w2b,
                                           xpad, w1pad, s_x, s_w, s_b, counts);
    gemm1_topk<<<dim3(64, 32, 2), 256, 0, stream>>>(xb, w1b, xpad, w1pad, b1, hbuf, counts);
    fixup_kernel<<<4096, 256, 0, stream>>>(x, W1, b1, counts, s_x, s_w, s_b, hbuf);
    gemm2_bias<<<dim3(64, 16), 256, 0, stream>>>(hbuf, w2b, b2, out);
}

// Round 2
// 300.017 us; speedup vs baseline: 1.0475x; 1.0475x over previous
//
#include <hip/hip_runtime.h>
#include <math.h>
#include <stdint.h>

// ---------------------------------------------------------------------------
// Mlp_8744553415182 on MI355X (gfx950). FP32 I/O; bf16 MFMA compute.
//   1. prep_kernel:  x->xb(+xpad,s_x), W1->w1b(+w1pad,s_w), W2->w2b, s_b, counts=0
//   2. gemm1_topk:   z=0: h = gelu(x.W1^T+b1) (256x256 tile, K=1024)
//                    z=1: counts[n] += #(x_topk.w1_topk+b1 > 0) (K=128)
//   3. fixup_kernel: channels with counts<=2048 -> exact quantized path
//   4. gemm2_bias:   out = h.W2^T + b2 (256x128 tile, K=4096)
// R7->R8: R7 grafted counted-vmcnt onto the 128^2 2-barrier core -> null/regress
// (guide regime-gate: T3/T4/T5 need the 256^2 8-wave structure). R8 ports the
// m201-style deep pipeline: 512 thr = 8 waves (2Mx4N), per-wave 128x(64|32)
// output, acc[8][NF]; LDS ring of 4 slots x one 32-k chunk (A 256x32 + B Nx32,
// 16-row x 32-k blocks in R3-verified XOR-swizzled layout); per chunk:
//   STAGE(c+3) -> s_waitcnt vmcnt(3*L) [chunks c+1..c+3 stay in flight,
//   NEVER drained mid-loop] -> s_barrier -> ds_read_b128 frags -> MFMA
//   cluster under setprio(1) -> s_barrier.   Tails: vmcnt(2L), (L), (0).
// Slot ledger: stage target (c+3)&3 == slot (c-1)&3, vacated at c-1's closing
// barrier (all waves passed before iter c issues). Per-wave load count uniform
// (4/chunk gemm1, 3/chunk gemm2) so vmcnt immediates are exact.
// Grid: blockIdx.x = N-block so XCD=id%8 pins each B panel in one XCD L2
// (R7 counter: gemm2 FETCH 77->173 MB was an L2/L3 locality regression).
// ---------------------------------------------------------------------------

typedef __bf16 v8bf __attribute__((ext_vector_type(8)));
typedef float v4f __attribute__((ext_vector_type(4)));
typedef unsigned short v8us __attribute__((ext_vector_type(8)));

#define AS_G __attribute__((address_space(1)))
#define AS_L __attribute__((address_space(3)))
#define GLOAD(gp, lp) __builtin_amdgcn_global_load_lds((const AS_G void*)(gp), (AS_L void*)(lp), 16, 0, 0)
#define WAITV(n) asm volatile("s_waitcnt vmcnt(" #n ")" ::: "memory")
#define FENCE() __builtin_amdgcn_sched_barrier(0)
#define BAR() __builtin_amdgcn_s_barrier()

__device__ __forceinline__ unsigned short f2bf(float f) {
    union { float f; unsigned int i; } v; v.f = f;
    unsigned int r = v.i + 0x7fffu + ((v.i >> 16) & 1u);   // RNE
    return (unsigned short)(r >> 16);
}
__device__ __forceinline__ float gelu_fast(float v) {
    float u = v * (0.79788456080286536f + 0.035677408136300125f * v * v);
    u = fminf(fmaxf(u, -15.f), 15.f);
    float e = __expf(2.0f * u);
    return v * e * __builtin_amdgcn_rcpf(e + 1.0f);   // v*e/(e+1) = 0.5v(1+tanh u)
}
__device__ __forceinline__ float gelu_exact(float v) {
    return 0.5f * v * (1.0f + erff(v * 0.70710678118654752440f));
}

// --------------------------- deep-pipelined 256-row MFMA core ---------------
// NB = number of 16-row B blocks (16 -> BN=256, NF=4 ; 8 -> BN=128, NF=2).
// Chunk = one 32-wide k-slice: 16 A blocks + NB B blocks, each block =
// 16 rows x 32 k bf16 = 1 KB, XOR-swizzled (writer: lane l sources global row
// l>>2, k-chunk ((l&3)^((l>>3)&3))*8, LDS linear lane*16B; reader:
// roff = R*32 + (Q^((R>>1)&3))*8, R=lane&15, Q=lane>>4 — R3-verified 0-confl).
// Ring of 4 chunk slots. Loads/wave/chunk L = (16+NB)/8.
template<int NB>
__device__ __forceinline__ void gemm_core8(const unsigned short* __restrict__ A,
                                           const unsigned short* __restrict__ B,
                                           const int K, const int NC,
                                           const int bm0, const int bn0,
                                           unsigned short* lds,
                                           v4f (&acc)[8][NB / 4])
{
    constexpr int NF = NB / 4;
    constexpr int CH = (16 + NB) * 512;        // shorts per ring slot
    const int tid  = threadIdx.x;
    const int wave = tid >> 6;                 // 0..7
    const int lane = tid & 63;
    const int wm = wave >> 2, wn = wave & 3;   // 2 x 4 wave grid
    const int rowInChunk = lane >> 2;
    const int col8 = ((lane & 3) ^ ((lane >> 3) & 3)) * 8;
    const int ldsLane = lane * 8;
    const int R = lane & 15, Q = lane >> 4;
    const int roff = R * 32 + ((Q ^ ((R >> 1) & 3)) * 8);

    const size_t aR0 = (size_t)(bm0 + (2 * wave)     * 16 + rowInChunk) * K + col8;
    const size_t aR1 = (size_t)(bm0 + (2 * wave + 1) * 16 + rowInChunk) * K + col8;
    size_t bR0 = 0, bR1 = 0;
    if constexpr (NB == 16) {
        bR0 = (size_t)(bn0 + (2 * wave)     * 16 + rowInChunk) * K + col8;
        bR1 = (size_t)(bn0 + (2 * wave + 1) * 16 + rowInChunk) * K + col8;
    } else {
        bR0 = (size_t)(bn0 + wave * 16 + rowInChunk) * K + col8;
    }

    auto STAGE = [&](int kc, unsigned short* s) {
        const int k0 = kc * 32;
        GLOAD(A + aR0 + k0, s + (2 * wave) * 512 + ldsLane);
        GLOAD(A + aR1 + k0, s + (2 * wave + 1) * 512 + ldsLane);
        if constexpr (NB == 16) {
            GLOAD(B + bR0 + k0, s + (16 + 2 * wave) * 512 + ldsLane);
            GLOAD(B + bR1 + k0, s + (16 + 2 * wave + 1) * 512 + ldsLane);
        } else {
            GLOAD(B + bR0 + k0, s + (16 + wave) * 512 + ldsLane);
        }
    };
    auto COMPUTE = [&](const unsigned short* s) {
        v8bf af[8], bf[NF];
#pragma unroll
        for (int mf = 0; mf < 8; ++mf)
            af[mf] = *(const v8bf*)&s[(wm * 8 + mf) * 512 + roff];
#pragma unroll
        for (int nf = 0; nf < NF; ++nf)
            bf[nf] = *(const v8bf*)&s[(16 + wn * NF + nf) * 512 + roff];
        __builtin_amdgcn_s_setprio(1);
#pragma unroll
        for (int mf = 0; mf < 8; ++mf)
#pragma unroll
            for (int nf = 0; nf < NF; ++nf)
                acc[mf][nf] = __builtin_amdgcn_mfma_f32_16x16x32_bf16(af[mf], bf[nf], acc[mf][nf], 0, 0, 0);
        __builtin_amdgcn_s_setprio(0);
    };

    unsigned short* const sl3 = lds + 3 * (size_t)CH;
    // prologue: chunks 0,1,2 -> slots 0,1,2
    STAGE(0, lds);
    STAGE(1, lds + CH);
    STAGE(2, lds + 2 * (size_t)CH);
    unsigned short* pc = lds;    // compute slot  (c   & 3)
    unsigned short* ps = sl3;    // stage slot    (c+3 & 3)

    for (int c = 0; c < NC - 3; ++c) {
        STAGE(c + 3, ps);
        if constexpr (NB == 16) WAITV(12); else WAITV(9);
        FENCE(); BAR(); FENCE();
        COMPUTE(pc);
        FENCE(); BAR(); FENCE();
        ps = pc;                                   // slot (c+4)&3 == (c)&3
        pc = (pc == sl3) ? lds : pc + CH;
    }
    // tail chunks NC-3, NC-2, NC-1
    if constexpr (NB == 16) WAITV(8); else WAITV(6);
    FENCE(); BAR(); FENCE();
    COMPUTE(pc);
    FENCE(); BAR(); FENCE();
    pc = (pc == sl3) ? lds : pc + CH;
    if constexpr (NB == 16) WAITV(4); else WAITV(3);
    FENCE(); BAR(); FENCE();
    COMPUTE(pc);
    FENCE(); BAR(); FENCE();
    pc = (pc == sl3) ? lds : pc + CH;
    WAITV(0);
    FENCE(); BAR(); FENCE();
    COMPUTE(pc);
    FENCE(); BAR(); FENCE();
}

// --------------------------- prep (fused) -----------------------------------
__global__ void prep_kernel(const float* __restrict__ x, const float* __restrict__ W1,
                            const float* __restrict__ W2, const float* __restrict__ b1,
                            unsigned short* __restrict__ xb, unsigned short* __restrict__ w1b,
                            unsigned short* __restrict__ w2b,
                            unsigned short* __restrict__ xpad, unsigned short* __restrict__ w1pad,
                            float* __restrict__ s_x, float* __restrict__ s_w,
                            float* __restrict__ s_b, int* __restrict__ counts)
{
    const int b = blockIdx.x, t = threadIdx.x;
    __shared__ float red[4];

    if (b < 16384) {
        const float* src; unsigned short* dst; unsigned short* pad = nullptr; float* sc = nullptr;
        if (b < 8192)       { src = x  + (size_t)b * 1024;            dst = xb  + (size_t)b * 1024;
                              pad = xpad  + (size_t)b * 128;          sc = s_x + b; }
        else if (b < 12288) { int r = b - 8192;  src = W1 + (size_t)r * 1024; dst = w1b + (size_t)r * 1024;
                              pad = w1pad + (size_t)r * 128;          sc = s_w + r; }
        else                { int r = b - 12288; src = W2 + (size_t)r * 1024; dst = w2b + (size_t)r * 1024; }

        float4 v = ((const float4*)src)[t];
        ushort4 u;
        u.x = f2bf(v.x); u.y = f2bf(v.y); u.z = f2bf(v.z); u.w = f2bf(v.w);
        ((ushort4*)dst)[t] = u;
        if (pad && t < 32) {
            int c = t * 4;
            ushort4 p;
            p.x = (c + 0 < 103) ? u.x : (unsigned short)0;
            p.y = (c + 1 < 103) ? u.y : (unsigned short)0;
            p.z = (c + 2 < 103) ? u.z : (unsigned short)0;
            p.w = (c + 3 < 103) ? u.w : (unsigned short)0;
            ((ushort4*)pad)[t] = p;
        }
        if (sc) {
            float m = fmaxf(fmaxf(fabsf(v.x), fabsf(v.y)), fmaxf(fabsf(v.z), fabsf(v.w)));
#pragma unroll
            for (int off = 32; off; off >>= 1) m = fmaxf(m, __shfl_xor(m, off, 64));
            if ((t & 63) == 0) red[t >> 6] = m;
            __syncthreads();
            if (t == 0) {
                m = fmaxf(fmaxf(red[0], red[1]), fmaxf(red[2], red[3]));
                *sc = fmaxf(m, 1e-5f) * (1.0f / 127.0f);
            }
        }
    } else {
        float m = 0.f;
        for (int k = t; k < 4096; k += 256) { m = fmaxf(m, fabsf(b1[k])); counts[k] = 0; }
#pragma unroll
        for (int off = 32; off; off >>= 1) m = fmaxf(m, __shfl_xor(m, off, 64));
        if ((t & 63) == 0) red[t >> 6] = m;
        __syncthreads();
        if (t == 0) {
            m = fmaxf(fmaxf(red[0], red[1]), fmaxf(red[2], red[3]));
            *s_b = fmaxf(m, 1e-5f) * (1.0f / 127.0f);
        }
    }
}

// --------------------------- gemm1 + topk (fused dispatch) -------------------
// grid (16, 32, 2): x = N-block (XCD = x%8 keeps each B panel on one XCD L2),
// y = M-block, z = path. 512 threads, 128 KB LDS, 1 block/CU.
__global__ __launch_bounds__(512, 2)
void gemm1_topk(const unsigned short* __restrict__ xb,
                const unsigned short* __restrict__ w1b,
                const unsigned short* __restrict__ xpad,
                const unsigned short* __restrict__ w1pad,
                const float* __restrict__ b1,
                unsigned short* __restrict__ hbuf,
                int* __restrict__ counts)
{
    __shared__ unsigned short lds[65536];   // 128 KB: 4 ring slots x 32 KB
    v4f acc[8][4];
    v4f z = {0.f, 0.f, 0.f, 0.f};
#pragma unroll
    for (int i = 0; i < 8; ++i)
#pragma unroll
        for (int j = 0; j < 4; ++j) acc[i][j] = z;

    const int bn0 = blockIdx.x * 256, bm0 = blockIdx.y * 256;
    const int tid = threadIdx.x;
    const int lane = tid & 63, wave = tid >> 6;
    const int wm = wave >> 2, wn = wave & 3, q = lane >> 4;

    if (blockIdx.z == 0) {
        gemm_core8<16>(xb, w1b, 1024, 32, bm0, bn0, lds, acc);

        float bvj[4];
#pragma unroll
        for (int nf = 0; nf < 4; ++nf) bvj[nf] = b1[bn0 + wn * 64 + nf * 16 + (lane & 15)];

        unsigned short* slab = lds;          // 64 x 256 bf16 slab = 32 KB
#pragma unroll
        for (int p = 0; p < 4; ++p) {
            __syncthreads();
            if (wm == (p >> 1)) {
                const int mfb = (p & 1) * 4;
#pragma unroll
                for (int mfp = 0; mfp < 4; ++mfp)
#pragma unroll
                    for (int nf = 0; nf < 4; ++nf) {
                        const int colq = wn * 64 + nf * 16 + (lane & 15);
#pragma unroll
                        for (int r = 0; r < 4; ++r)
                            slab[(mfp * 16 + q * 4 + r) * 256 + colq] =
                                f2bf(gelu_fast(acc[mfb + mfp][nf][r] + bvj[nf]));
                    }
            }
            __syncthreads();
#pragma unroll
            for (int s = 0; s < 4; ++s) {
                const int idx = s * 512 + tid;          // 0..2047
                const int row = idx >> 5, ch = idx & 31;
                *(v8us*)&hbuf[(size_t)(bm0 + p * 64 + row) * 4096 + bn0 + ch * 8] =
                    *(const v8us*)&slab[row * 256 + ch * 8];
            }
        }
    } else {
        gemm_core8<16>(xpad, w1pad, 128, 4, bm0, bn0, lds, acc);

#pragma unroll
        for (int nf = 0; nf < 4; ++nf) {
            const int n = bn0 + wn * 64 + nf * 16 + (lane & 15);
            const float bv = b1[n];
            int cnt = 0;
#pragma unroll
            for (int mf = 0; mf < 8; ++mf)
#pragma unroll
                for (int r = 0; r < 4; ++r)
                    cnt += (acc[mf][nf][r] + bv > 0.0f) ? 1 : 0;
            cnt += __shfl_xor(cnt, 16, 64);
            cnt += __shfl_xor(cnt, 32, 64);
            if (lane < 16 && cnt) atomicAdd(&counts[n], cnt);
        }
    }
}

// --------------------------- fixup (exact quant path) ------------------------
__global__ void fixup_kernel(const float* __restrict__ x,
                             const float* __restrict__ W1,
                             const float* __restrict__ b1,
                             const int* __restrict__ counts,
                             const float* __restrict__ s_x,
                             const float* __restrict__ s_w,
                             const float* __restrict__ s_b,
                             unsigned short* __restrict__ hbuf)
{
    const int n = blockIdx.x;
    if (counts[n] > 2048) return;   // fp channel: keep gemm1 result
    __shared__ float qw[1024];
    const float swn = s_w[n];
    for (int k = threadIdx.x; k < 1024; k += 256) {
        float q = nearbyintf(W1[(size_t)n * 1024 + k] / swn);
        qw[k] = fminf(fmaxf(q, -128.f), 127.f) * swn;
    }
    __syncthreads();
    const float sb = *s_b;
    const float bq = fminf(fmaxf(nearbyintf(b1[n] / sb), -128.f), 127.f) * sb;
    for (int m = threadIdx.x; m < 8192; m += 256) {
        const float sxm = s_x[m];
        float a = 0.f;
        for (int k = 0; k < 1024; ++k) {
            float q = nearbyintf(x[(size_t)m * 1024 + k] / sxm);
            a += fminf(fmaxf(q, -128.f), 127.f) * sxm * qw[k];
        }
        hbuf[(size_t)m * 4096 + n] = f2bf(gelu_exact(a + bq));
    }
}

// --------------------------- gemm2 + bias (256x128 tile) ---------------------
// grid (8, 32): x = N-block -> XCD = x: each 1 MB W2 panel L2-resident on its
// XCD. 256 blocks, 1/CU, 96 KB LDS ring. FP32 slab epilogue, float4 out.
__global__ __launch_bounds__(512, 2)
void gemm2_bias(const unsigned short* __restrict__ hbuf,
                const unsigned short* __restrict__ w2b,
                const float* __restrict__ b2,
                float* __restrict__ out)
{
    __shared__ unsigned short lds[49152];   // 96 KB: 4 ring slots x 24 KB
    v4f acc[8][2];
    v4f z = {0.f, 0.f, 0.f, 0.f};
#pragma unroll
    for (int i = 0; i < 8; ++i)
#pragma unroll
        for (int j = 0; j < 2; ++j) acc[i][j] = z;

    const int bn0 = blockIdx.x * 128, bm0 = blockIdx.y * 256;
    const int tid = threadIdx.x;
    const int lane = tid & 63, wave = tid >> 6;
    const int wm = wave >> 2, wn = wave & 3, q = lane >> 4;

    gemm_core8<8>(hbuf, w2b, 4096, 128, bm0, bn0, lds, acc);

    float bvj[2];
#pragma unroll
    for (int nf = 0; nf < 2; ++nf) bvj[nf] = b2[bn0 + wn * 32 + nf * 16 + (lane & 15)];

    float* slabf = (float*)lds;             // 64 x 128 fp32 slab = 32 KB
#pragma unroll
    for (int p = 0; p < 4; ++p) {
        __syncthreads();
        if (wm == (p >> 1)) {
            const int mfb = (p & 1) * 4;
#pragma unroll
            for (int mfp = 0; mfp < 4; ++mfp)
#pragma unroll
                for (int nf = 0; nf < 2; ++nf) {
                    const int colq = wn * 32 + nf * 16 + (lane & 15);
#pragma unroll
                    for (int r = 0; r < 4; ++r)
                        slabf[(mfp * 16 + q * 4 + r) * 128 + colq] =
                            acc[mfb + mfp][nf][r] + bvj[nf];
                }
        }
        __syncthreads();
#pragma unroll
        for (int s = 0; s < 4; ++s) {
            const int idx = s * 512 + tid;           // 0..2047
            const int row = idx >> 5, ch = idx & 31; // 64 rows x 32 float4
            *(float4*)&out[(size_t)(bm0 + p * 64 + row) * 1024 + bn0 + ch * 4] =
                *(const float4*)&slabf[row * 128 + ch * 4];
        }
    }
}

// --------------------------- launch ----------------------------------------
extern "C" void kernel_launch(void* const* d_in, const int* in_sizes, int n_in,
                              void* d_out, int out_size, void* d_ws, size_t ws_size,
                              hipStream_t stream)
{
    const float* x  = (const float*)d_in[0];   // [4,2048,1024] fp32
    const float* W1 = (const float*)d_in[1];   // [4096,1024]
    const float* b1 = (const float*)d_in[2];   // [4096]
    const float* W2 = (const float*)d_in[3];   // [1024,4096]
    const float* b2 = (const float*)d_in[4];   // [1024]
    float* out = (float*)d_out;                // [4,2048,1024] fp32 (32 MB)

    // bf16 copies of x and W1 parked in d_out (dead until gemm2 writes it):
    unsigned short* xb  = (unsigned short*)d_out;                       // 16 MB
    unsigned short* w1b = (unsigned short*)d_out + (size_t)8192 * 1024; // 8 MB

    char* ws = (char*)d_ws;
    int*   counts = (int*)(ws + 0);                       // 16 KB
    float* s_x    = (float*)(ws + (64 << 10));            // 32 KB
    float* s_w    = (float*)(ws + (96 << 10));            // 16 KB
    float* s_b    = (float*)(ws + (112 << 10));           // 4 B
    unsigned short* xpad  = (unsigned short*)(ws + (1 << 20));   // 2 MB
    unsigned short* w1pad = (unsigned short*)(ws + (3 << 20));   // 1 MB
    unsigned short* w2b   = (unsigned short*)(ws + (4 << 20));   // 8 MB
    unsigned short* hbuf  = (unsigned short*)(ws + (12 << 20));  // 64 MB -> 76 MB total

    prep_kernel<<<16385, 256, 0, stream>>>(x, W1, W2, b1, xb, w1b, w2b,
                                           xpad, w1pad, s_x, s_w, s_b, counts);
    gemm1_topk<<<dim3(16, 32, 2), 512, 0, stream>>>(xb, w1b, xpad, w1pad, b1, hbuf, counts);
    fixup_kernel<<<4096, 256, 0, stream>>>(x, W1, b1, counts, s_x, s_w, s_b, hbuf);
    gemm2_bias<<<dim3(8, 32), 512, 0, stream>>>(hbuf, w2b, b2, out);
}